// Round 10
// baseline (266.237 us; speedup 1.0000x reference)
//
#include <hip/hip_runtime.h>
#include <hip/hip_bf16.h>
#include <math.h>

#define NB 4
#define NN 128
#define NF 128
#define NS 5
#define NT 32
#define NL 2

typedef __hip_bfloat16 bf16;
typedef short bf16x8 __attribute__((ext_vector_type(8)));
typedef float f32x4 __attribute__((ext_vector_type(4)));

__device__ __forceinline__ float b2f(const bf16 x) { return __bfloat162float(x); }
__device__ __forceinline__ float fast_rcp(float x) { return __builtin_amdgcn_rcpf(x); }
__device__ __forceinline__ float fast_rsq(float x) { return __builtin_amdgcn_rsqf(x); }
__device__ __forceinline__ float silu_fast(float x) { return x * fast_rcp(1.0f + __expf(-x)); }
__device__ __forceinline__ float ldf(const void* p, int i, int fl) {
  return fl ? b2f(((const bf16*)p)[i]) : ((const float*)p)[i];
}
// float -> bf16 bits (RNE)
__device__ __forceinline__ short f2bf(float x) {
  unsigned u = __float_as_uint(x);
  unsigned r = (u + 0x7fffu + ((u >> 16) & 1u)) >> 16;
  return (short)r;
}

#define PI_F 3.14159265358979323846f
#define SQRT3_F 1.7320508075688772f

// converted-weights region offsets (floats) within d_ws after the flag slot
#define POS_OFF 0
#define GF_OFF  1536
#define WE_OFF  1664
#define BE_OFF  6400
#define WR1_OFF 6528
#define BR1_OFF 6656
#define WR2_OFF 6784
#define WN_OFF  72320
#define C1_OFF  105088
#define C2_OFF  106112
#define C3_OFF  107136
#define M0_OFF  108160
#define M1_OFF  140928
#define G1_OFF  173696
#define G2_OFF  177792
#define WV_OFF  181888
#define CVT_TOTAL 182144

// ---------------------------------------------------------------------------
// prep_convert: unchanged from round 9 (known-good).
// ---------------------------------------------------------------------------
__global__ void prep_convert_kernel(
    const void* __restrict__ pos_raw, const int* __restrict__ nfeat,
    const void* __restrict__ gf,  const void* __restrict__ we,
    const void* __restrict__ be,  const void* __restrict__ wr1,
    const void* __restrict__ br1, const void* __restrict__ wr2,
    const void* __restrict__ wn,  const void* __restrict__ c1,
    const void* __restrict__ c2,  const void* __restrict__ c3,
    const void* __restrict__ m0,  const void* __restrict__ m1,
    const void* __restrict__ g1,  const void* __restrict__ g2,
    const void* __restrict__ wv,
    int* __restrict__ flag, float* __restrict__ cvt,
    float* __restrict__ pos_cur, float* __restrict__ z,
    float* __restrict__ vec, float* __restrict__ env,
    float* __restrict__ Ag)
{
  __shared__ float posB[NN*3];
  __shared__ float scs[NF];
  __shared__ int sbad;
  const int tid = threadIdx.x;
  const int bn  = blockIdx.x;        // node row, 0..511
  const int b   = bn >> 7;
  const int n   = bn & 127;

  if (tid == 0) sbad = 0;
  __syncthreads();
  {
    const bf16* p = (const bf16*)pos_raw;
    int bad = 0;
    for (int i = tid; i < NB*NN*3; i += 256) {
      float v = b2f(p[i]);
      if (!(fabsf(v) <= 1024.0f)) bad = 1;   // NaN also fails
    }
    if (bad) sbad = 1;
  }
  __syncthreads();
  const int fl = sbad ? 0 : 1;               // 1 = bf16 inputs
  if (bn == 0 && tid == 0) *flag = fl;

  for (int i = bn*256 + tid; i < CVT_TOTAL; i += 512*256) {
    const void* src; int j;
    if      (i < GF_OFF)  { src = pos_raw; j = i - POS_OFF; }
    else if (i < WE_OFF)  { src = gf;  j = i - GF_OFF; }
    else if (i < BE_OFF)  { src = we;  j = i - WE_OFF; }
    else if (i < WR1_OFF) { src = be;  j = i - BE_OFF; }
    else if (i < BR1_OFF) { src = wr1; j = i - WR1_OFF; }
    else if (i < WR2_OFF) { src = br1; j = i - BR1_OFF; }
    else if (i < WN_OFF)  { src = wr2; j = i - WR2_OFF; }
    else if (i < C1_OFF)  { src = wn;  j = i - WN_OFF; }
    else if (i < C2_OFF)  { src = c1;  j = i - C1_OFF; }
    else if (i < C3_OFF)  { src = c2;  j = i - C2_OFF; }
    else if (i < M0_OFF)  { src = c3;  j = i - C3_OFF; }
    else if (i < M1_OFF)  { src = m0;  j = i - M0_OFF; }
    else if (i < G1_OFF)  { src = m1;  j = i - M1_OFF; }
    else if (i < G2_OFF)  { src = g1;  j = i - G1_OFF; }
    else if (i < WV_OFF)  { src = g2;  j = i - G2_OFF; }
    else                  { src = wv;  j = i - WV_OFF; }
    cvt[i] = fl ? b2f(((const bf16*)src)[j]) : ((const float*)src)[j];
  }

  for (int i = tid; i < NN*3; i += 256)
    posB[i] = ldf(pos_raw, b*NN*3 + i, fl);
  if (tid < 128) {
    int sp = nfeat[bn] - 1;
    float acc = ldf(we, sp*NF + tid, fl) + ldf(be, tid, fl);
    #pragma unroll 8
    for (int t = 0; t < NT; ++t)
      acc += ldf(gf, b*NT + t, fl) * ldf(we, (NS + t)*NF + tid, fl);
    scs[tid] = acc;
  }
  __syncthreads();

  if (tid < 128) {
    const int f = tid;
    {
      float px = posB[n*3+0], py = posB[n*3+1], pz = posB[n*3+2];
      float vx = px - posB[f*3+0];
      float vy = py - posB[f*3+1];
      float vz = pz - posB[f*3+2];
      float lng = sqrtf(vx*vx + vy*vy + vz*vz + 1e-12f);
      env[bn*NN + f] = (lng < 10.0f) ? 0.5f*(cosf(PI_F*lng*0.1f) + 1.0f) : 0.0f;
    }
    {
      float acc = 0.f;
      if (fl) {
        const bf16* W = (const bf16*)wn;
        #pragma unroll 8
        for (int k = 0; k < NF; ++k) acc += scs[k] * b2f(W[k*NF + f]);
      } else {
        const float* W = (const float*)wn;
        #pragma unroll 8
        for (int k = 0; k < NF; ++k) acc += scs[k] * W[k*NF + f];
      }
      z[bn*NF + f] = acc;
    }
    vec[((size_t)bn*3 + 0)*NF + f] = 0.f;
    vec[((size_t)bn*3 + 1)*NF + f] = 0.f;
    vec[((size_t)bn*3 + 2)*NF + f] = 0.f;
    float* Arow = Ag + (size_t)bn*4*NF;
    #pragma unroll
    for (int c = 0; c < 4; ++c) Arow[c*NF + f] = 0.f;
    if (f < 3) pos_cur[bn*3 + f] = posB[n*3 + f];
  }
}

// ---------------------------------------------------------------------------
// EDGE v7 (MFMA): grid = 1024 blocks (b, 4-receiver tile, 16-sender group).
// Radial GEMM Hid[16edges x 64] @ Wr2[64 x 256] per chunk via
// mfma_f32_16x16x32_bf16 (2 K-steps). Layouts (m89/m120-verified):
//   A[m=lane&15][k=quad*8+j]  -> hid staged bf16 in LDS, row stride 72
//   B[n=lane&15][k=quad*8+j]  -> Wr2 cols in 32 VGPRs/thread (sqrt3 folded)
//   C: col=lane&15, row=quad*4+reg -> edge = quarter(receiver)*4 + reg(sender)
// Consume: per-lane (receiver=quarter) sums 4 sender contributions, then one
// race-free LDS RMW per (c, col) into block accumulator Acc[16][128].
// Epilogue: 8 global atomicAdds per thread.
// ---------------------------------------------------------------------------
__global__ __launch_bounds__(256, 2)
void edge_kernel(const float* __restrict__ pos_cur,
                 const float* __restrict__ z,
                 const float* __restrict__ vec,
                 const float* __restrict__ env,
                 const float* __restrict__ cvt,
                 int layer, float* __restrict__ Ag)
{
  __shared__ float posL[NN*3];                   // 1.5 KB
  __shared__ float envL[4][16];
  __shared__ float w1L[64], b1L[64];
  __shared__ __align__(16) short hidA[16][72];   // bf16 A tile, padded stride
  __shared__ __align__(16) float4 zvp[4][NF];    // 8 KB {z,vx,vy,vz} per (s,f)
  __shared__ __align__(16) float4 uenvL[4][4];   // [r][si] {ux,uy,uz,env/16}
  __shared__ float Acc[16][NF];                  // 8 KB [c*4+r][f]

  const int tid  = threadIdx.x;
  const int bidx = blockIdx.x;                   // b*256 + rt*8 + sg
  const int b    = bidx >> 8;
  const int rt   = (bidx >> 3) & 31;
  const int sg   = bidx & 7;
  const int r0   = rt * 4;
  const int sbase= sg * 16;

  const int wv    = tid >> 6;                    // wave id 0..3
  const int lane  = tid & 63;
  const int n16   = lane & 15;                   // MFMA n / A-row index
  const int q     = lane >> 4;                   // quarter
  const int halfB = wv >> 1;                     // 0: ell0 cols, 1: ell1 cols

  // ---- prologue ----
  for (int i = tid; i < NN*3; i += 256)
    posL[i] = pos_cur[b*NN*3 + i];
  if (tid < 64) {
    int rr = tid >> 4, j = tid & 15;
    envL[rr][j] = env[(b*NN + r0 + rr)*NN + sbase + j];
    w1L[tid] = cvt[WR1_OFF + layer*64 + tid];
    b1L[tid] = cvt[BR1_OFF + layer*64 + tid];
  }
  // zero block accumulator
  {
    float* A1 = &Acc[0][0];
    #pragma unroll
    for (int j = 0; j < 8; ++j) A1[tid + j*256] = 0.f;
  }
  // B fragments: Wr2 cols for this wave's 4 N-tiles, both K-steps, bf16
  bf16x8 bfr[4][2];
  {
    const float* W2 = cvt + WR2_OFF + layer*64*512;
    #pragma unroll
    for (int t = 0; t < 4; ++t) {
      int col = wv*64 + t*16 + n16;              // 0..255
      #pragma unroll
      for (int ks = 0; ks < 2; ++ks) {
        #pragma unroll
        for (int j = 0; j < 8; ++j) {
          int k = ks*32 + q*8 + j;
          float v = W2[k*512 + col];
          if (halfB) v *= SQRT3_F;
          bfr[t][ks][j] = f2bf(v);
        }
      }
    }
  }
  __syncthreads();

  const int rme = wv;                            // receiver staged by this wave
  const int hme = lane;                          // hidden unit 0..63
  const float hrx = posL[(r0 + rme)*3 + 0];
  const float hry = posL[(r0 + rme)*3 + 1];
  const float hrz = posL[(r0 + rme)*3 + 2];
  const float w1v = w1L[hme], b1v = b1L[hme];

  for (int c0 = 0; c0 < 16; c0 += 4) {
    // ---- stage z/vec as float4 per (sender, f): coalesced loads ----
    #pragma unroll
    for (int rep = 0; rep < 2; ++rep) {
      int idx = tid + rep*256;                   // 0..511
      int si = idx >> 7, f = idx & 127;
      int gs = b*NN + sbase + c0 + si;
      float zz = z[gs*NF + f];
      float v0 = vec[((size_t)gs*3 + 0)*NF + f];
      float v1 = vec[((size_t)gs*3 + 1)*NF + f];
      float v2 = vec[((size_t)gs*3 + 2)*NF + f];
      zvp[si][f] = make_float4(zz, v0, v1, v2);
    }
    // ---- stage radial-hidden as bf16 A tile: edge = r*4 + si ----
    #pragma unroll
    for (int si = 0; si < 4; ++si) {
      int s = sbase + c0 + si;
      float vx = hrx - posL[s*3 + 0];
      float vy = hry - posL[s*3 + 1];
      float vz = hrz - posL[s*3 + 2];
      float d = vx*vx + vy*vy + vz*vz + 1e-12f;
      float lng = d * fast_rsq(d);
      hidA[rme*4 + si][hme] = f2bf(silu_fast(lng * w1v + b1v));
    }
    // ---- stage u + env weight per (r, si) ----
    if (tid < 16) {
      int r = tid >> 2, si = tid & 3;
      int s = sbase + c0 + si;
      float vx = posL[(r0 + r)*3 + 0] - posL[s*3 + 0];
      float vy = posL[(r0 + r)*3 + 1] - posL[s*3 + 1];
      float vz = posL[(r0 + r)*3 + 2] - posL[s*3 + 2];
      float d = vx*vx + vy*vy + vz*vz + 1e-12f;
      float inv = fast_rsq(d);
      float envw = (s == r0 + r) ? 0.f : envL[r][c0 + si] * 0.0625f;
      uenvL[r][si] = make_float4(vx*inv, vy*inv, vz*inv, envw);
    }
    __syncthreads();

    // ---- MFMA radial GEMM + consume ----
    bf16x8 af0 = *(const bf16x8*)&hidA[n16][q*8];        // K-step 0
    bf16x8 af1 = *(const bf16x8*)&hidA[n16][q*8 + 32];   // K-step 1
    float4 ue[4];
    #pragma unroll
    for (int si = 0; si < 4; ++si) ue[si] = uenvL[q][si];

    #pragma unroll
    for (int t = 0; t < 4; ++t) {
      f32x4 Cf = {0.f, 0.f, 0.f, 0.f};
      Cf = __builtin_amdgcn_mfma_f32_16x16x32_bf16(af0, bfr[t][0], Cf, 0, 0, 0);
      Cf = __builtin_amdgcn_mfma_f32_16x16x32_bf16(af1, bfr[t][1], Cf, 0, 0, 0);
      int f = (wv*64 + t*16 + n16) & 127;        // feature index
      if (!halfB) {
        float a0 = 0.f;
        #pragma unroll
        for (int si = 0; si < 4; ++si) {
          float4 zv = zvp[si][f];
          float fv = zv.x + ue[si].x*zv.y + ue[si].y*zv.z + ue[si].z*zv.w;
          a0 += (Cf[si] * ue[si].w) * fv;        // C row = q*4+si -> edge(q,si)
        }
        Acc[q][f] += a0;                         // c=0, r=q
      } else {
        float t1 = 0.f, t2 = 0.f, t3 = 0.f;
        #pragma unroll
        for (int si = 0; si < 4; ++si) {
          float4 zv = zvp[si][f];
          float fv = zv.x + ue[si].x*zv.y + ue[si].y*zv.z + ue[si].z*zv.w;
          float tt = (Cf[si] * ue[si].w) * fv;   // sqrt3 folded into B
          t1 += tt * ue[si].x;
          t2 += tt * ue[si].y;
          t3 += tt * ue[si].z;
        }
        Acc[4  + q][f] += t1;                    // c=1, r=q
        Acc[8  + q][f] += t2;                    // c=2
        Acc[12 + q][f] += t3;                    // c=3
      }
    }
    __syncthreads();
  }

  // ---- epilogue: 8 atomics per thread ----
  #pragma unroll
  for (int j = 0; j < 8; ++j) {
    int i = tid*8 + j;                           // 0..2047
    int row16 = i >> 7, f = i & 127;
    int c = row16 >> 2, r = row16 & 3;
    atomicAdd(Ag + ((size_t)(b*NN + r0 + r)*4 + c)*NF + f, Acc[row16][f]);
  }
}

// ---------------------------------------------------------------------------
// NODE: unchanged from round 9 (known-good).
// ---------------------------------------------------------------------------
__global__ void node_kernel(float* __restrict__ Ag,
                            const float* __restrict__ cvt,
                            int layer, int last,
                            float* __restrict__ vec,
                            float* __restrict__ z,
                            float* __restrict__ pos_cur,
                            const int* __restrict__ flag,
                            void* __restrict__ out)
{
  int bn = blockIdx.x;
  int f  = threadIdx.x;   // 0..127
  __shared__ float Ash[4][NF];
  __shared__ float scs[NF];
  __shared__ float h16[16];
  __shared__ float red[2][4];

  {
    float* Arow = Ag + (size_t)bn*4*NF;
    float a0 = Arow[0*NF + f];
    float a1 = Arow[1*NF + f];
    float a2 = Arow[2*NF + f];
    float a3 = Arow[3*NF + f];
    Arow[0*NF + f] = 0.f;
    Arow[1*NF + f] = 0.f;
    Arow[2*NF + f] = 0.f;
    Arow[3*NF + f] = 0.f;
    float n0 = a0*a0;
    float C1 = cvt[C1_OFF + (layer*4 + 0)*NF + f];
    float C2 = cvt[C2_OFF + (layer*4 + 0)*NF + f];
    float C3 = cvt[C3_OFF + (layer*4 + 0)*NF + f];
    float g0 = 1.0f + C1*n0 + C2*n0*n0 + C3*n0*n0*n0;
    float n1 = a1*a1 + a2*a2 + a3*a3;
    float D1 = cvt[C1_OFF + (layer*4 + 1)*NF + f];
    float D2 = cvt[C2_OFF + (layer*4 + 1)*NF + f];
    float D3 = cvt[C3_OFF + (layer*4 + 1)*NF + f];
    float g1 = 1.0f + D1*n1 + D2*n1*n1 + D3*n1*n1*n1;
    Ash[0][f] = a0 * g0;
    Ash[1][f] = a1 * g1;
    Ash[2][f] = a2 * g1;
    Ash[3][f] = a3 * g1;
  }
  __syncthreads();

  const float* M0 = cvt + M0_OFF + layer*NF*NF;
  const float* M1 = cvt + M1_OFF + layer*NF*NF;
  float sn = 0.f, v0 = 0.f, v1 = 0.f, v2 = 0.f;
  #pragma unroll 4
  for (int k = 0; k < NF; ++k) {
    float m0 = M0[k*NF + f];
    float m1 = M1[k*NF + f];
    sn += Ash[0][k] * m0;
    v0 += Ash[1][k] * m1;
    v1 += Ash[2][k] * m1;
    v2 += Ash[3][k] * m1;
  }
  scs[f] = sn;
  __syncthreads();

  if (!last) {
    const float* W = cvt + WN_OFF + (layer+1)*NF*NF;
    float acc = 0.f;
    #pragma unroll 8
    for (int k = 0; k < NF; ++k)
      acc += scs[k] * W[k*NF + f];
    z[bn*NF + f] = acc;
  }

  if (f < 16) {
    const float* G1 = cvt + G1_OFF + layer*NF*16;
    float acc = 0.f;
    #pragma unroll 8
    for (int k = 0; k < NF; ++k)
      acc += scs[k] * G1[k*16 + f];
    h16[f] = silu_fast(acc);
  }
  __syncthreads();
  const float* G2 = cvt + G2_OFF + layer*16*NF;
  float gate = 0.f;
  #pragma unroll
  for (int j = 0; j < 16; ++j)
    gate += h16[j] * G2[j*NF + f];
  float gv = gate * cvt[WV_OFF + layer*NF + f];

  vec[((size_t)bn*3 + 0)*NF + f] = v0;
  vec[((size_t)bn*3 + 1)*NF + f] = v1;
  vec[((size_t)bn*3 + 2)*NF + f] = v2;

  float p0 = v0*gv, p1 = v1*gv, p2 = v2*gv;
  #pragma unroll
  for (int off = 32; off > 0; off >>= 1) {
    p0 += __shfl_down(p0, off, 64);
    p1 += __shfl_down(p1, off, 64);
    p2 += __shfl_down(p2, off, 64);
  }
  int wave = f >> 6;
  if ((f & 63) == 0) { red[wave][0] = p0; red[wave][1] = p1; red[wave][2] = p2; }
  __syncthreads();
  if (f == 0) {
    float m0 = red[0][0] + red[1][0];
    float m1 = red[0][1] + red[1][1];
    float m2 = red[0][2] + red[1][2];
    float px = pos_cur[bn*3+0] + m0;
    float py = pos_cur[bn*3+1] + m1;
    float pz = pos_cur[bn*3+2] + m2;
    pos_cur[bn*3+0] = px;
    pos_cur[bn*3+1] = py;
    pos_cur[bn*3+2] = pz;
    if (last) {
      float ox = px - cvt[POS_OFF + bn*3+0];
      float oy = py - cvt[POS_OFF + bn*3+1];
      float oz = pz - cvt[POS_OFF + bn*3+2];
      if (*flag) {
        bf16* o = (bf16*)out;
        o[bn*3+0] = __float2bfloat16(ox);
        o[bn*3+1] = __float2bfloat16(oy);
        o[bn*3+2] = __float2bfloat16(oz);
      } else {
        float* o = (float*)out;
        o[bn*3+0] = ox;
        o[bn*3+1] = oy;
        o[bn*3+2] = oz;
      }
    }
  }
}

// ---------------------------------------------------------------------------
extern "C" void kernel_launch(void* const* d_in, const int* in_sizes, int n_in,
                              void* d_out, int out_size, void* d_ws, size_t ws_size,
                              hipStream_t stream)
{
  (void)in_sizes; (void)n_in; (void)out_size; (void)ws_size;
  const int* nfeat = (const int*)d_in[1];

  float* ws      = (float*)d_ws;
  int*   flag    = (int*)ws;                  // 16 floats reserved
  float* cvt     = ws + 16;                   // CVT_TOTAL floats
  float* pos_cur = cvt + CVT_TOTAL;           // 1536
  float* z       = pos_cur + NB*NN*3;         // 65536
  float* vec     = z + NB*NN*NF;              // 196608
  float* Ag      = vec + NB*NN*3*NF;          // 262144
  float* env     = Ag + NB*NN*4*NF;           // 65536

  prep_convert_kernel<<<512, 256, 0, stream>>>(
      d_in[0], nfeat, d_in[2], d_in[3], d_in[4], d_in[5], d_in[6], d_in[7],
      d_in[8], d_in[9], d_in[10], d_in[11], d_in[12], d_in[13], d_in[14],
      d_in[15], d_in[16], flag, cvt, pos_cur, z, vec, env, Ag);
  for (int i = 0; i < NL; ++i) {
    edge_kernel<<<1024, 256, 0, stream>>>(pos_cur, z, vec, env, cvt, i, Ag);
    node_kernel<<<NB*NN, NF, 0, stream>>>(Ag, cvt, i, (i == NL-1) ? 1 : 0,
                                          vec, z, pos_cur, flag, d_out);
  }
}

// Round 11
// 181.147 us; speedup vs baseline: 1.4697x; 1.4697x over previous
//
#include <hip/hip_runtime.h>
#include <hip/hip_bf16.h>
#include <math.h>

#define NB 4
#define NN 128
#define NF 128
#define NS 5
#define NT 32
#define NL 2

typedef __hip_bfloat16 bf16;
typedef short bf16x8 __attribute__((ext_vector_type(8)));
typedef float f32x4 __attribute__((ext_vector_type(4)));

__device__ __forceinline__ float b2f(const bf16 x) { return __bfloat162float(x); }
__device__ __forceinline__ float fast_rcp(float x) { return __builtin_amdgcn_rcpf(x); }
__device__ __forceinline__ float fast_rsq(float x) { return __builtin_amdgcn_rsqf(x); }
__device__ __forceinline__ float silu_fast(float x) { return x * fast_rcp(1.0f + __expf(-x)); }
__device__ __forceinline__ float ldf(const void* p, int i, int fl) {
  return fl ? b2f(((const bf16*)p)[i]) : ((const float*)p)[i];
}
// float -> bf16 bits (RNE)
__device__ __forceinline__ short f2bf(float x) {
  unsigned u = __float_as_uint(x);
  unsigned r = (u + 0x7fffu + ((u >> 16) & 1u)) >> 16;
  return (short)r;
}

#define PI_F 3.14159265358979323846f
#define SQRT3_F 1.7320508075688772f

// converted-weights region offsets (floats) within d_ws after the flag slot
#define POS_OFF 0
#define GF_OFF  1536
#define WE_OFF  1664
#define BE_OFF  6400
#define WR1_OFF 6528
#define BR1_OFF 6656
#define WR2_OFF 6784
#define WN_OFF  72320
#define C1_OFF  105088
#define C2_OFF  106112
#define C3_OFF  107136
#define M0_OFF  108160
#define M1_OFF  140928
#define G1_OFF  173696
#define G2_OFF  177792
#define WV_OFF  181888
#define CVT_TOTAL 182144

// ---------------------------------------------------------------------------
// prep_convert: unchanged (known-good).
// ---------------------------------------------------------------------------
__global__ void prep_convert_kernel(
    const void* __restrict__ pos_raw, const int* __restrict__ nfeat,
    const void* __restrict__ gf,  const void* __restrict__ we,
    const void* __restrict__ be,  const void* __restrict__ wr1,
    const void* __restrict__ br1, const void* __restrict__ wr2,
    const void* __restrict__ wn,  const void* __restrict__ c1,
    const void* __restrict__ c2,  const void* __restrict__ c3,
    const void* __restrict__ m0,  const void* __restrict__ m1,
    const void* __restrict__ g1,  const void* __restrict__ g2,
    const void* __restrict__ wv,
    int* __restrict__ flag, float* __restrict__ cvt,
    float* __restrict__ pos_cur, float* __restrict__ z,
    float* __restrict__ vec, float* __restrict__ env,
    float* __restrict__ Ag)
{
  __shared__ float posB[NN*3];
  __shared__ float scs[NF];
  __shared__ int sbad;
  const int tid = threadIdx.x;
  const int bn  = blockIdx.x;        // node row, 0..511
  const int b   = bn >> 7;
  const int n   = bn & 127;

  if (tid == 0) sbad = 0;
  __syncthreads();
  {
    const bf16* p = (const bf16*)pos_raw;
    int bad = 0;
    for (int i = tid; i < NB*NN*3; i += 256) {
      float v = b2f(p[i]);
      if (!(fabsf(v) <= 1024.0f)) bad = 1;   // NaN also fails
    }
    if (bad) sbad = 1;
  }
  __syncthreads();
  const int fl = sbad ? 0 : 1;               // 1 = bf16 inputs
  if (bn == 0 && tid == 0) *flag = fl;

  for (int i = bn*256 + tid; i < CVT_TOTAL; i += 512*256) {
    const void* src; int j;
    if      (i < GF_OFF)  { src = pos_raw; j = i - POS_OFF; }
    else if (i < WE_OFF)  { src = gf;  j = i - GF_OFF; }
    else if (i < BE_OFF)  { src = we;  j = i - WE_OFF; }
    else if (i < WR1_OFF) { src = be;  j = i - BE_OFF; }
    else if (i < BR1_OFF) { src = wr1; j = i - WR1_OFF; }
    else if (i < WR2_OFF) { src = br1; j = i - BR1_OFF; }
    else if (i < WN_OFF)  { src = wr2; j = i - WR2_OFF; }
    else if (i < C1_OFF)  { src = wn;  j = i - WN_OFF; }
    else if (i < C2_OFF)  { src = c1;  j = i - C1_OFF; }
    else if (i < C3_OFF)  { src = c2;  j = i - C2_OFF; }
    else if (i < M0_OFF)  { src = c3;  j = i - C3_OFF; }
    else if (i < M1_OFF)  { src = m0;  j = i - M0_OFF; }
    else if (i < G1_OFF)  { src = m1;  j = i - M1_OFF; }
    else if (i < G2_OFF)  { src = g1;  j = i - G1_OFF; }
    else if (i < WV_OFF)  { src = g2;  j = i - G2_OFF; }
    else                  { src = wv;  j = i - WV_OFF; }
    cvt[i] = fl ? b2f(((const bf16*)src)[j]) : ((const float*)src)[j];
  }

  for (int i = tid; i < NN*3; i += 256)
    posB[i] = ldf(pos_raw, b*NN*3 + i, fl);
  if (tid < 128) {
    int sp = nfeat[bn] - 1;
    float acc = ldf(we, sp*NF + tid, fl) + ldf(be, tid, fl);
    #pragma unroll 8
    for (int t = 0; t < NT; ++t)
      acc += ldf(gf, b*NT + t, fl) * ldf(we, (NS + t)*NF + tid, fl);
    scs[tid] = acc;
  }
  __syncthreads();

  if (tid < 128) {
    const int f = tid;
    {
      float px = posB[n*3+0], py = posB[n*3+1], pz = posB[n*3+2];
      float vx = px - posB[f*3+0];
      float vy = py - posB[f*3+1];
      float vz = pz - posB[f*3+2];
      float lng = sqrtf(vx*vx + vy*vy + vz*vz + 1e-12f);
      env[bn*NN + f] = (lng < 10.0f) ? 0.5f*(cosf(PI_F*lng*0.1f) + 1.0f) : 0.0f;
    }
    {
      float acc = 0.f;
      if (fl) {
        const bf16* W = (const bf16*)wn;
        #pragma unroll 8
        for (int k = 0; k < NF; ++k) acc += scs[k] * b2f(W[k*NF + f]);
      } else {
        const float* W = (const float*)wn;
        #pragma unroll 8
        for (int k = 0; k < NF; ++k) acc += scs[k] * W[k*NF + f];
      }
      z[bn*NF + f] = acc;
    }
    vec[((size_t)bn*3 + 0)*NF + f] = 0.f;
    vec[((size_t)bn*3 + 1)*NF + f] = 0.f;
    vec[((size_t)bn*3 + 2)*NF + f] = 0.f;
    float* Arow = Ag + (size_t)bn*4*NF;
    #pragma unroll
    for (int c = 0; c < 4; ++c) Arow[c*NF + f] = 0.f;
    if (f < 3) pos_cur[bn*3 + f] = posB[n*3 + f];
  }
}

// ---------------------------------------------------------------------------
// EDGE v8 (MFMA + VGPR accumulation): grid = 1024 blocks.
// Changes vs v7 (which was bound by 64MB atomic write traffic + LDS RMW
// conflicts): partial A sums live in VGPRs across chunks (no Acc LDS RMW);
// epilogue atomics issued with 16-consecutive-f lanes per quarter so each
// instruction touches 4 full 64B lines (HW merges same-line atomics).
// ---------------------------------------------------------------------------
__global__ __launch_bounds__(256, 2)
void edge_kernel(const float* __restrict__ pos_cur,
                 const float* __restrict__ z,
                 const float* __restrict__ vec,
                 const float* __restrict__ env,
                 const float* __restrict__ cvt,
                 int layer, float* __restrict__ Ag)
{
  __shared__ float posL[NN*3];                   // 1.5 KB
  __shared__ float envL[4][16];
  __shared__ float w1L[64], b1L[64];
  __shared__ __align__(16) short hidA[16][72];   // bf16 A tile, padded stride
  __shared__ __align__(16) float4 zvp[4][NF];    // 8 KB {z,vx,vy,vz} per (s,f)
  __shared__ __align__(16) float4 uenvL[4][4];   // [r][si] {ux,uy,uz,env/16}

  const int tid  = threadIdx.x;
  const int bidx = blockIdx.x;                   // b*256 + rt*8 + sg
  const int b    = bidx >> 8;
  const int rt   = (bidx >> 3) & 31;
  const int sg   = bidx & 7;
  const int r0   = rt * 4;
  const int sbase= sg * 16;

  const int wvid  = tid >> 6;                    // wave id 0..3
  const int lane  = tid & 63;
  const int n16   = lane & 15;                   // MFMA n / A-row index
  const int q     = lane >> 4;                   // quarter -> receiver
  const int halfB = wvid >> 1;                   // 0: ell0 cols, 1: ell1 cols

  // ---- prologue ----
  for (int i = tid; i < NN*3; i += 256)
    posL[i] = pos_cur[b*NN*3 + i];
  if (tid < 64) {
    int rr = tid >> 4, j = tid & 15;
    envL[rr][j] = env[(b*NN + r0 + rr)*NN + sbase + j];
    w1L[tid] = cvt[WR1_OFF + layer*64 + tid];
    b1L[tid] = cvt[BR1_OFF + layer*64 + tid];
  }
  // B fragments: Wr2 cols for this wave's 4 N-tiles, both K-steps, bf16
  bf16x8 bfr[4][2];
  {
    const float* W2 = cvt + WR2_OFF + layer*64*512;
    #pragma unroll
    for (int t = 0; t < 4; ++t) {
      int col = wvid*64 + t*16 + n16;            // 0..255
      #pragma unroll
      for (int ks = 0; ks < 2; ++ks) {
        #pragma unroll
        for (int j = 0; j < 8; ++j) {
          int k = ks*32 + q*8 + j;
          float v = W2[k*512 + col];
          if (halfB) v *= SQRT3_F;
          bfr[t][ks][j] = f2bf(v);
        }
      }
    }
  }
  // VGPR accumulators across chunks:
  //  halfB==0: acR[t]          (c=0)
  //  halfB==1: acR[t*3 + c-1]  (c=1..3)
  float acR[12];
  #pragma unroll
  for (int i = 0; i < 12; ++i) acR[i] = 0.f;

  __syncthreads();

  const int rme = wvid;                          // receiver staged by this wave
  const int hme = lane;                          // hidden unit 0..63
  const float hrx = posL[(r0 + rme)*3 + 0];
  const float hry = posL[(r0 + rme)*3 + 1];
  const float hrz = posL[(r0 + rme)*3 + 2];
  const float w1v = w1L[hme], b1v = b1L[hme];

  for (int c0 = 0; c0 < 16; c0 += 4) {
    // ---- stage z/vec as float4 per (sender, f) ----
    #pragma unroll
    for (int rep = 0; rep < 2; ++rep) {
      int idx = tid + rep*256;                   // 0..511
      int si = idx >> 7, f = idx & 127;
      int gs = b*NN + sbase + c0 + si;
      float zz = z[gs*NF + f];
      float v0 = vec[((size_t)gs*3 + 0)*NF + f];
      float v1 = vec[((size_t)gs*3 + 1)*NF + f];
      float v2 = vec[((size_t)gs*3 + 2)*NF + f];
      zvp[si][f] = make_float4(zz, v0, v1, v2);
    }
    // ---- stage radial-hidden as bf16 A tile: edge = r*4 + si ----
    #pragma unroll
    for (int si = 0; si < 4; ++si) {
      int s = sbase + c0 + si;
      float vx = hrx - posL[s*3 + 0];
      float vy = hry - posL[s*3 + 1];
      float vz = hrz - posL[s*3 + 2];
      float d = vx*vx + vy*vy + vz*vz + 1e-12f;
      float lng = d * fast_rsq(d);
      hidA[rme*4 + si][hme] = f2bf(silu_fast(lng * w1v + b1v));
    }
    // ---- stage u + env weight per (r, si) ----
    if (tid < 16) {
      int r = tid >> 2, si = tid & 3;
      int s = sbase + c0 + si;
      float vx = posL[(r0 + r)*3 + 0] - posL[s*3 + 0];
      float vy = posL[(r0 + r)*3 + 1] - posL[s*3 + 1];
      float vz = posL[(r0 + r)*3 + 2] - posL[s*3 + 2];
      float d = vx*vx + vy*vy + vz*vz + 1e-12f;
      float inv = fast_rsq(d);
      float envw = (s == r0 + r) ? 0.f : envL[r][c0 + si] * 0.0625f;
      uenvL[r][si] = make_float4(vx*inv, vy*inv, vz*inv, envw);
    }
    __syncthreads();

    // ---- MFMA radial GEMM + consume into VGPR accumulators ----
    bf16x8 af0 = *(const bf16x8*)&hidA[n16][q*8];        // K-step 0
    bf16x8 af1 = *(const bf16x8*)&hidA[n16][q*8 + 32];   // K-step 1
    float4 ue[4];
    #pragma unroll
    for (int si = 0; si < 4; ++si) ue[si] = uenvL[q][si];

    #pragma unroll
    for (int t = 0; t < 4; ++t) {
      f32x4 Cf = {0.f, 0.f, 0.f, 0.f};
      Cf = __builtin_amdgcn_mfma_f32_16x16x32_bf16(af0, bfr[t][0], Cf, 0, 0, 0);
      Cf = __builtin_amdgcn_mfma_f32_16x16x32_bf16(af1, bfr[t][1], Cf, 0, 0, 0);
      int f = (wvid*64 + t*16 + n16) & 127;      // feature index
      if (!halfB) {
        float a0 = 0.f;
        #pragma unroll
        for (int si = 0; si < 4; ++si) {
          float4 zv = zvp[si][f];
          float fv = zv.x + ue[si].x*zv.y + ue[si].y*zv.z + ue[si].z*zv.w;
          a0 += (Cf[si] * ue[si].w) * fv;        // C row = q*4+si -> edge(q,si)
        }
        acR[t] += a0;
      } else {
        float t1 = 0.f, t2 = 0.f, t3 = 0.f;
        #pragma unroll
        for (int si = 0; si < 4; ++si) {
          float4 zv = zvp[si][f];
          float fv = zv.x + ue[si].x*zv.y + ue[si].y*zv.z + ue[si].z*zv.w;
          float tt = (Cf[si] * ue[si].w) * fv;   // sqrt3 folded into B
          t1 += tt * ue[si].x;
          t2 += tt * ue[si].y;
          t3 += tt * ue[si].z;
        }
        acR[t*3 + 0] += t1;
        acR[t*3 + 1] += t2;
        acR[t*3 + 2] += t3;
      }
    }
    __syncthreads();
  }

  // ---- epilogue: coalesced atomics straight from VGPRs ----
  // Per instruction: quarter's 16 lanes hit 16 consecutive floats (one 64B
  // line); 4 lines per wave -> HW merges same-line atomics.
  const size_t rowbase = (size_t)(b*NN + r0 + q)*4;   // receiver q
  if (!halfB) {
    #pragma unroll
    for (int t = 0; t < 4; ++t) {
      int f = (wvid*64 + t*16 + n16) & 127;
      atomicAdd(Ag + (rowbase + 0)*NF + f, acR[t]);
    }
  } else {
    #pragma unroll
    for (int t = 0; t < 4; ++t) {
      int f = (wvid*64 + t*16 + n16) & 127;
      atomicAdd(Ag + (rowbase + 1)*NF + f, acR[t*3 + 0]);
      atomicAdd(Ag + (rowbase + 2)*NF + f, acR[t*3 + 1]);
      atomicAdd(Ag + (rowbase + 3)*NF + f, acR[t*3 + 2]);
    }
  }
}

// ---------------------------------------------------------------------------
// NODE: unchanged (known-good).
// ---------------------------------------------------------------------------
__global__ void node_kernel(float* __restrict__ Ag,
                            const float* __restrict__ cvt,
                            int layer, int last,
                            float* __restrict__ vec,
                            float* __restrict__ z,
                            float* __restrict__ pos_cur,
                            const int* __restrict__ flag,
                            void* __restrict__ out)
{
  int bn = blockIdx.x;
  int f  = threadIdx.x;   // 0..127
  __shared__ float Ash[4][NF];
  __shared__ float scs[NF];
  __shared__ float h16[16];
  __shared__ float red[2][4];

  {
    float* Arow = Ag + (size_t)bn*4*NF;
    float a0 = Arow[0*NF + f];
    float a1 = Arow[1*NF + f];
    float a2 = Arow[2*NF + f];
    float a3 = Arow[3*NF + f];
    Arow[0*NF + f] = 0.f;
    Arow[1*NF + f] = 0.f;
    Arow[2*NF + f] = 0.f;
    Arow[3*NF + f] = 0.f;
    float n0 = a0*a0;
    float C1 = cvt[C1_OFF + (layer*4 + 0)*NF + f];
    float C2 = cvt[C2_OFF + (layer*4 + 0)*NF + f];
    float C3 = cvt[C3_OFF + (layer*4 + 0)*NF + f];
    float g0 = 1.0f + C1*n0 + C2*n0*n0 + C3*n0*n0*n0;
    float n1 = a1*a1 + a2*a2 + a3*a3;
    float D1 = cvt[C1_OFF + (layer*4 + 1)*NF + f];
    float D2 = cvt[C2_OFF + (layer*4 + 1)*NF + f];
    float D3 = cvt[C3_OFF + (layer*4 + 1)*NF + f];
    float g1 = 1.0f + D1*n1 + D2*n1*n1 + D3*n1*n1*n1;
    Ash[0][f] = a0 * g0;
    Ash[1][f] = a1 * g1;
    Ash[2][f] = a2 * g1;
    Ash[3][f] = a3 * g1;
  }
  __syncthreads();

  const float* M0 = cvt + M0_OFF + layer*NF*NF;
  const float* M1 = cvt + M1_OFF + layer*NF*NF;
  float sn = 0.f, v0 = 0.f, v1 = 0.f, v2 = 0.f;
  #pragma unroll 4
  for (int k = 0; k < NF; ++k) {
    float m0 = M0[k*NF + f];
    float m1 = M1[k*NF + f];
    sn += Ash[0][k] * m0;
    v0 += Ash[1][k] * m1;
    v1 += Ash[2][k] * m1;
    v2 += Ash[3][k] * m1;
  }
  scs[f] = sn;
  __syncthreads();

  if (!last) {
    const float* W = cvt + WN_OFF + (layer+1)*NF*NF;
    float acc = 0.f;
    #pragma unroll 8
    for (int k = 0; k < NF; ++k)
      acc += scs[k] * W[k*NF + f];
    z[bn*NF + f] = acc;
  }

  if (f < 16) {
    const float* G1 = cvt + G1_OFF + layer*NF*16;
    float acc = 0.f;
    #pragma unroll 8
    for (int k = 0; k < NF; ++k)
      acc += scs[k] * G1[k*16 + f];
    h16[f] = silu_fast(acc);
  }
  __syncthreads();
  const float* G2 = cvt + G2_OFF + layer*16*NF;
  float gate = 0.f;
  #pragma unroll
  for (int j = 0; j < 16; ++j)
    gate += h16[j] * G2[j*NF + f];
  float gv = gate * cvt[WV_OFF + layer*NF + f];

  vec[((size_t)bn*3 + 0)*NF + f] = v0;
  vec[((size_t)bn*3 + 1)*NF + f] = v1;
  vec[((size_t)bn*3 + 2)*NF + f] = v2;

  float p0 = v0*gv, p1 = v1*gv, p2 = v2*gv;
  #pragma unroll
  for (int off = 32; off > 0; off >>= 1) {
    p0 += __shfl_down(p0, off, 64);
    p1 += __shfl_down(p1, off, 64);
    p2 += __shfl_down(p2, off, 64);
  }
  int wave = f >> 6;
  if ((f & 63) == 0) { red[wave][0] = p0; red[wave][1] = p1; red[wave][2] = p2; }
  __syncthreads();
  if (f == 0) {
    float m0 = red[0][0] + red[1][0];
    float m1 = red[0][1] + red[1][1];
    float m2 = red[0][2] + red[1][2];
    float px = pos_cur[bn*3+0] + m0;
    float py = pos_cur[bn*3+1] + m1;
    float pz = pos_cur[bn*3+2] + m2;
    pos_cur[bn*3+0] = px;
    pos_cur[bn*3+1] = py;
    pos_cur[bn*3+2] = pz;
    if (last) {
      float ox = px - cvt[POS_OFF + bn*3+0];
      float oy = py - cvt[POS_OFF + bn*3+1];
      float oz = pz - cvt[POS_OFF + bn*3+2];
      if (*flag) {
        bf16* o = (bf16*)out;
        o[bn*3+0] = __float2bfloat16(ox);
        o[bn*3+1] = __float2bfloat16(oy);
        o[bn*3+2] = __float2bfloat16(oz);
      } else {
        float* o = (float*)out;
        o[bn*3+0] = ox;
        o[bn*3+1] = oy;
        o[bn*3+2] = oz;
      }
    }
  }
}

// ---------------------------------------------------------------------------
extern "C" void kernel_launch(void* const* d_in, const int* in_sizes, int n_in,
                              void* d_out, int out_size, void* d_ws, size_t ws_size,
                              hipStream_t stream)
{
  (void)in_sizes; (void)n_in; (void)out_size; (void)ws_size;
  const int* nfeat = (const int*)d_in[1];

  float* ws      = (float*)d_ws;
  int*   flag    = (int*)ws;                  // 16 floats reserved
  float* cvt     = ws + 16;                   // CVT_TOTAL floats
  float* pos_cur = cvt + CVT_TOTAL;           // 1536
  float* z       = pos_cur + NB*NN*3;         // 65536
  float* vec     = z + NB*NN*NF;              // 196608
  float* Ag      = vec + NB*NN*3*NF;          // 262144
  float* env     = Ag + NB*NN*4*NF;           // 65536

  prep_convert_kernel<<<512, 256, 0, stream>>>(
      d_in[0], nfeat, d_in[2], d_in[3], d_in[4], d_in[5], d_in[6], d_in[7],
      d_in[8], d_in[9], d_in[10], d_in[11], d_in[12], d_in[13], d_in[14],
      d_in[15], d_in[16], flag, cvt, pos_cur, z, vec, env, Ag);
  for (int i = 0; i < NL; ++i) {
    edge_kernel<<<1024, 256, 0, stream>>>(pos_cur, z, vec, env, cvt, i, Ag);
    node_kernel<<<NB*NN, NF, 0, stream>>>(Ag, cvt, i, (i == NL-1) ? 1 : 0,
                                          vec, z, pos_cur, flag, d_out);
  }
}

// Round 12
// 178.969 us; speedup vs baseline: 1.4876x; 1.0122x over previous
//
#include <hip/hip_runtime.h>
#include <hip/hip_bf16.h>
#include <math.h>

#define NB 4
#define NN 128
#define NF 128
#define NS 5
#define NT 32
#define NL 2

typedef __hip_bfloat16 bf16;
typedef short bf16x8 __attribute__((ext_vector_type(8)));
typedef float f32x4 __attribute__((ext_vector_type(4)));

__device__ __forceinline__ float b2f(const bf16 x) { return __bfloat162float(x); }
__device__ __forceinline__ float fast_rcp(float x) { return __builtin_amdgcn_rcpf(x); }
__device__ __forceinline__ float fast_rsq(float x) { return __builtin_amdgcn_rsqf(x); }
__device__ __forceinline__ float silu_fast(float x) { return x * fast_rcp(1.0f + __expf(-x)); }
__device__ __forceinline__ float ldf(const void* p, int i, int fl) {
  return fl ? b2f(((const bf16*)p)[i]) : ((const float*)p)[i];
}
// float -> bf16 bits (RNE)
__device__ __forceinline__ short f2bf(float x) {
  unsigned u = __float_as_uint(x);
  unsigned r = (u + 0x7fffu + ((u >> 16) & 1u)) >> 16;
  return (short)r;
}

#define PI_F 3.14159265358979323846f
#define SQRT3_F 1.7320508075688772f

// converted-weights region offsets (floats) within d_ws after the flag slot
#define POS_OFF 0
#define GF_OFF  1536
#define WE_OFF  1664
#define BE_OFF  6400
#define WR1_OFF 6528
#define BR1_OFF 6656
#define WR2_OFF 6784
#define WN_OFF  72320
#define C1_OFF  105088
#define C2_OFF  106112
#define C3_OFF  107136
#define M0_OFF  108160
#define M1_OFF  140928
#define G1_OFF  173696
#define G2_OFF  177792
#define WV_OFF  181888
#define CVT_TOTAL 182144

// ---------------------------------------------------------------------------
// prep_convert: unchanged (known-good).
// ---------------------------------------------------------------------------
__global__ void prep_convert_kernel(
    const void* __restrict__ pos_raw, const int* __restrict__ nfeat,
    const void* __restrict__ gf,  const void* __restrict__ we,
    const void* __restrict__ be,  const void* __restrict__ wr1,
    const void* __restrict__ br1, const void* __restrict__ wr2,
    const void* __restrict__ wn,  const void* __restrict__ c1,
    const void* __restrict__ c2,  const void* __restrict__ c3,
    const void* __restrict__ m0,  const void* __restrict__ m1,
    const void* __restrict__ g1,  const void* __restrict__ g2,
    const void* __restrict__ wv,
    int* __restrict__ flag, float* __restrict__ cvt,
    float* __restrict__ pos_cur, float* __restrict__ z,
    float* __restrict__ vec, float* __restrict__ env,
    float* __restrict__ Ag)
{
  __shared__ float posB[NN*3];
  __shared__ float scs[NF];
  __shared__ int sbad;
  const int tid = threadIdx.x;
  const int bn  = blockIdx.x;        // node row, 0..511
  const int b   = bn >> 7;
  const int n   = bn & 127;

  if (tid == 0) sbad = 0;
  __syncthreads();
  {
    const bf16* p = (const bf16*)pos_raw;
    int bad = 0;
    for (int i = tid; i < NB*NN*3; i += 256) {
      float v = b2f(p[i]);
      if (!(fabsf(v) <= 1024.0f)) bad = 1;   // NaN also fails
    }
    if (bad) sbad = 1;
  }
  __syncthreads();
  const int fl = sbad ? 0 : 1;               // 1 = bf16 inputs
  if (bn == 0 && tid == 0) *flag = fl;

  for (int i = bn*256 + tid; i < CVT_TOTAL; i += 512*256) {
    const void* src; int j;
    if      (i < GF_OFF)  { src = pos_raw; j = i - POS_OFF; }
    else if (i < WE_OFF)  { src = gf;  j = i - GF_OFF; }
    else if (i < BE_OFF)  { src = we;  j = i - WE_OFF; }
    else if (i < WR1_OFF) { src = be;  j = i - BE_OFF; }
    else if (i < BR1_OFF) { src = wr1; j = i - WR1_OFF; }
    else if (i < WR2_OFF) { src = br1; j = i - BR1_OFF; }
    else if (i < WN_OFF)  { src = wr2; j = i - WR2_OFF; }
    else if (i < C1_OFF)  { src = wn;  j = i - WN_OFF; }
    else if (i < C2_OFF)  { src = c1;  j = i - C1_OFF; }
    else if (i < C3_OFF)  { src = c2;  j = i - C2_OFF; }
    else if (i < M0_OFF)  { src = c3;  j = i - C3_OFF; }
    else if (i < M1_OFF)  { src = m0;  j = i - M0_OFF; }
    else if (i < G1_OFF)  { src = m1;  j = i - M1_OFF; }
    else if (i < G2_OFF)  { src = g1;  j = i - G1_OFF; }
    else if (i < WV_OFF)  { src = g2;  j = i - G2_OFF; }
    else                  { src = wv;  j = i - WV_OFF; }
    cvt[i] = fl ? b2f(((const bf16*)src)[j]) : ((const float*)src)[j];
  }

  for (int i = tid; i < NN*3; i += 256)
    posB[i] = ldf(pos_raw, b*NN*3 + i, fl);
  if (tid < 128) {
    int sp = nfeat[bn] - 1;
    float acc = ldf(we, sp*NF + tid, fl) + ldf(be, tid, fl);
    #pragma unroll 8
    for (int t = 0; t < NT; ++t)
      acc += ldf(gf, b*NT + t, fl) * ldf(we, (NS + t)*NF + tid, fl);
    scs[tid] = acc;
  }
  __syncthreads();

  if (tid < 128) {
    const int f = tid;
    {
      float px = posB[n*3+0], py = posB[n*3+1], pz = posB[n*3+2];
      float vx = px - posB[f*3+0];
      float vy = py - posB[f*3+1];
      float vz = pz - posB[f*3+2];
      float lng = sqrtf(vx*vx + vy*vy + vz*vz + 1e-12f);
      env[bn*NN + f] = (lng < 10.0f) ? 0.5f*(cosf(PI_F*lng*0.1f) + 1.0f) : 0.0f;
    }
    {
      float acc = 0.f;
      if (fl) {
        const bf16* W = (const bf16*)wn;
        #pragma unroll 8
        for (int k = 0; k < NF; ++k) acc += scs[k] * b2f(W[k*NF + f]);
      } else {
        const float* W = (const float*)wn;
        #pragma unroll 8
        for (int k = 0; k < NF; ++k) acc += scs[k] * W[k*NF + f];
      }
      z[bn*NF + f] = acc;
    }
    vec[((size_t)bn*3 + 0)*NF + f] = 0.f;
    vec[((size_t)bn*3 + 1)*NF + f] = 0.f;
    vec[((size_t)bn*3 + 2)*NF + f] = 0.f;
    float* Arow = Ag + (size_t)bn*4*NF;
    #pragma unroll
    for (int c = 0; c < 4; ++c) Arow[c*NF + f] = 0.f;
    if (f < 3) pos_cur[bn*3 + f] = posB[n*3 + f];
  }
}

// ---------------------------------------------------------------------------
// EDGE v9 (MFMA + VGPR accum + software pipeline): grid = 1024 blocks.
// vs v8: hidA/zvp/uenv double-buffered; chunk c+1's global z/vec loads issue
// into registers before chunk c's MFMA+consume; one barrier per chunk (5 vs
// 8). Epilogue (coalesced atomics) and all numerics identical to v8.
// ---------------------------------------------------------------------------
__global__ __launch_bounds__(256, 2)
void edge_kernel(const float* __restrict__ pos_cur,
                 const float* __restrict__ z,
                 const float* __restrict__ vec,
                 const float* __restrict__ env,
                 const float* __restrict__ cvt,
                 int layer, float* __restrict__ Ag)
{
  __shared__ float posL[NN*3];                     // 1.5 KB
  __shared__ float envL[4][16];
  __shared__ float w1L[64], b1L[64];
  __shared__ __align__(16) short hidA[2][16][72];  // 4.5 KB bf16 A tiles
  __shared__ __align__(16) float4 zvp[2][4][NF];   // 16 KB
  __shared__ __align__(16) float4 uenvL[2][4][4];  // [buf][r][si]

  const int tid  = threadIdx.x;
  const int bidx = blockIdx.x;                   // b*256 + rt*8 + sg
  const int b    = bidx >> 8;
  const int rt   = (bidx >> 3) & 31;
  const int sg   = bidx & 7;
  const int r0   = rt * 4;
  const int sbase= sg * 16;

  const int wvid  = tid >> 6;                    // wave id 0..3
  const int lane  = tid & 63;
  const int n16   = lane & 15;                   // MFMA n / A-row index
  const int q     = lane >> 4;                   // quarter -> receiver
  const int halfB = wvid >> 1;                   // 0: ell0 cols, 1: ell1 cols

  // ---- prologue ----
  for (int i = tid; i < NN*3; i += 256)
    posL[i] = pos_cur[b*NN*3 + i];
  if (tid < 64) {
    int rr = tid >> 4, j = tid & 15;
    envL[rr][j] = env[(b*NN + r0 + rr)*NN + sbase + j];
    w1L[tid] = cvt[WR1_OFF + layer*64 + tid];
    b1L[tid] = cvt[BR1_OFF + layer*64 + tid];
  }
  // B fragments: Wr2 cols for this wave's 4 N-tiles, both K-steps, bf16
  bf16x8 bfr[4][2];
  {
    const float* W2 = cvt + WR2_OFF + layer*64*512;
    #pragma unroll
    for (int t = 0; t < 4; ++t) {
      int col = wvid*64 + t*16 + n16;            // 0..255
      #pragma unroll
      for (int ks = 0; ks < 2; ++ks) {
        #pragma unroll
        for (int j = 0; j < 8; ++j) {
          int k = ks*32 + q*8 + j;
          float v = W2[k*512 + col];
          if (halfB) v *= SQRT3_F;
          bfr[t][ks][j] = f2bf(v);
        }
      }
    }
  }
  float acR[12];
  #pragma unroll
  for (int i = 0; i < 12; ++i) acR[i] = 0.f;

  __syncthreads();   // posL/envL/w1L ready

  const int rme = wvid;                          // receiver staged by this wave
  const int hme = lane;                          // hidden unit 0..63
  const float hrx = posL[(r0 + rme)*3 + 0];
  const float hry = posL[(r0 + rme)*3 + 1];
  const float hrz = posL[(r0 + rme)*3 + 2];
  const float w1v = w1L[hme], b1v = b1L[hme];

  const int fS  = tid & 127;                     // staging column
  const int si0 = tid >> 7;                      // staging sender base (0/1)

  float4 pv[2];                                  // prefetch registers

  // ---- stage chunk 0 ----
  #pragma unroll
  for (int rep = 0; rep < 2; ++rep) {
    int gs = b*NN + sbase + 0 + si0 + 2*rep;
    pv[rep].x = z[gs*NF + fS];
    pv[rep].y = vec[((size_t)gs*3 + 0)*NF + fS];
    pv[rep].z = vec[((size_t)gs*3 + 1)*NF + fS];
    pv[rep].w = vec[((size_t)gs*3 + 2)*NF + fS];
  }
  #pragma unroll
  for (int si = 0; si < 4; ++si) {
    int s = sbase + si;
    float vx = hrx - posL[s*3 + 0];
    float vy = hry - posL[s*3 + 1];
    float vz = hrz - posL[s*3 + 2];
    float d = vx*vx + vy*vy + vz*vz + 1e-12f;
    float lng = d * fast_rsq(d);
    hidA[0][rme*4 + si][hme] = f2bf(silu_fast(lng * w1v + b1v));
  }
  if (tid < 16) {
    int r = tid >> 2, si = tid & 3;
    int s = sbase + si;
    float vx = posL[(r0 + r)*3 + 0] - posL[s*3 + 0];
    float vy = posL[(r0 + r)*3 + 1] - posL[s*3 + 1];
    float vz = posL[(r0 + r)*3 + 2] - posL[s*3 + 2];
    float d = vx*vx + vy*vy + vz*vz + 1e-12f;
    float inv = fast_rsq(d);
    float envw = (s == r0 + r) ? 0.f : envL[r][si] * 0.0625f;
    uenvL[0][r][si] = make_float4(vx*inv, vy*inv, vz*inv, envw);
  }
  #pragma unroll
  for (int rep = 0; rep < 2; ++rep)
    zvp[0][si0 + 2*rep][fS] = pv[rep];
  __syncthreads();

  // ---- pipelined chunk loop: 1 barrier per chunk ----
  #pragma unroll
  for (int c = 0; c < 4; ++c) {
    const int cb = c & 1, nb = cb ^ 1;
    const int nc0 = (c + 1) * 4;

    // issue next chunk's global loads first (latency hidden under MFMA)
    if (c < 3) {
      #pragma unroll
      for (int rep = 0; rep < 2; ++rep) {
        int gs = b*NN + sbase + nc0 + si0 + 2*rep;
        pv[rep].x = z[gs*NF + fS];
        pv[rep].y = vec[((size_t)gs*3 + 0)*NF + fS];
        pv[rep].z = vec[((size_t)gs*3 + 1)*NF + fS];
        pv[rep].w = vec[((size_t)gs*3 + 2)*NF + fS];
      }
    }

    // ---- MFMA radial GEMM + consume (buffer cb) ----
    bf16x8 af0 = *(const bf16x8*)&hidA[cb][n16][q*8];
    bf16x8 af1 = *(const bf16x8*)&hidA[cb][n16][q*8 + 32];
    float4 ue[4];
    #pragma unroll
    for (int si = 0; si < 4; ++si) ue[si] = uenvL[cb][q][si];

    #pragma unroll
    for (int t = 0; t < 4; ++t) {
      f32x4 Cf = {0.f, 0.f, 0.f, 0.f};
      Cf = __builtin_amdgcn_mfma_f32_16x16x32_bf16(af0, bfr[t][0], Cf, 0, 0, 0);
      Cf = __builtin_amdgcn_mfma_f32_16x16x32_bf16(af1, bfr[t][1], Cf, 0, 0, 0);
      int f = (wvid*64 + t*16 + n16) & 127;      // feature index
      if (!halfB) {
        float a0 = 0.f;
        #pragma unroll
        for (int si = 0; si < 4; ++si) {
          float4 zv = zvp[cb][si][f];
          float fv = zv.x + ue[si].x*zv.y + ue[si].y*zv.z + ue[si].z*zv.w;
          a0 += (Cf[si] * ue[si].w) * fv;        // C row = q*4+si -> edge(q,si)
        }
        acR[t] += a0;
      } else {
        float t1 = 0.f, t2 = 0.f, t3 = 0.f;
        #pragma unroll
        for (int si = 0; si < 4; ++si) {
          float4 zv = zvp[cb][si][f];
          float fv = zv.x + ue[si].x*zv.y + ue[si].y*zv.z + ue[si].z*zv.w;
          float tt = (Cf[si] * ue[si].w) * fv;   // sqrt3 folded into B
          t1 += tt * ue[si].x;
          t2 += tt * ue[si].y;
          t3 += tt * ue[si].z;
        }
        acR[t*3 + 0] += t1;
        acR[t*3 + 1] += t2;
        acR[t*3 + 2] += t3;
      }
    }

    // ---- stage next chunk into buffer nb ----
    if (c < 3) {
      #pragma unroll
      for (int si = 0; si < 4; ++si) {
        int s = sbase + nc0 + si;
        float vx = hrx - posL[s*3 + 0];
        float vy = hry - posL[s*3 + 1];
        float vz = hrz - posL[s*3 + 2];
        float d = vx*vx + vy*vy + vz*vz + 1e-12f;
        float lng = d * fast_rsq(d);
        hidA[nb][rme*4 + si][hme] = f2bf(silu_fast(lng * w1v + b1v));
      }
      if (tid < 16) {
        int r = tid >> 2, si = tid & 3;
        int s = sbase + nc0 + si;
        float vx = posL[(r0 + r)*3 + 0] - posL[s*3 + 0];
        float vy = posL[(r0 + r)*3 + 1] - posL[s*3 + 1];
        float vz = posL[(r0 + r)*3 + 2] - posL[s*3 + 2];
        float d = vx*vx + vy*vy + vz*vz + 1e-12f;
        float inv = fast_rsq(d);
        float envw = (s == r0 + r) ? 0.f : envL[r][nc0 + si] * 0.0625f;
        uenvL[nb][r][si] = make_float4(vx*inv, vy*inv, vz*inv, envw);
      }
      #pragma unroll
      for (int rep = 0; rep < 2; ++rep)
        zvp[nb][si0 + 2*rep][fS] = pv[rep];
    }
    __syncthreads();
  }

  // ---- epilogue: coalesced atomics straight from VGPRs ----
  const size_t rowbase = (size_t)(b*NN + r0 + q)*4;   // receiver q
  if (!halfB) {
    #pragma unroll
    for (int t = 0; t < 4; ++t) {
      int f = (wvid*64 + t*16 + n16) & 127;
      atomicAdd(Ag + (rowbase + 0)*NF + f, acR[t]);
    }
  } else {
    #pragma unroll
    for (int t = 0; t < 4; ++t) {
      int f = (wvid*64 + t*16 + n16) & 127;
      atomicAdd(Ag + (rowbase + 1)*NF + f, acR[t*3 + 0]);
      atomicAdd(Ag + (rowbase + 2)*NF + f, acR[t*3 + 1]);
      atomicAdd(Ag + (rowbase + 3)*NF + f, acR[t*3 + 2]);
    }
  }
}

// ---------------------------------------------------------------------------
// NODE: unchanged (known-good).
// ---------------------------------------------------------------------------
__global__ void node_kernel(float* __restrict__ Ag,
                            const float* __restrict__ cvt,
                            int layer, int last,
                            float* __restrict__ vec,
                            float* __restrict__ z,
                            float* __restrict__ pos_cur,
                            const int* __restrict__ flag,
                            void* __restrict__ out)
{
  int bn = blockIdx.x;
  int f  = threadIdx.x;   // 0..127
  __shared__ float Ash[4][NF];
  __shared__ float scs[NF];
  __shared__ float h16[16];
  __shared__ float red[2][4];

  {
    float* Arow = Ag + (size_t)bn*4*NF;
    float a0 = Arow[0*NF + f];
    float a1 = Arow[1*NF + f];
    float a2 = Arow[2*NF + f];
    float a3 = Arow[3*NF + f];
    Arow[0*NF + f] = 0.f;
    Arow[1*NF + f] = 0.f;
    Arow[2*NF + f] = 0.f;
    Arow[3*NF + f] = 0.f;
    float n0 = a0*a0;
    float C1 = cvt[C1_OFF + (layer*4 + 0)*NF + f];
    float C2 = cvt[C2_OFF + (layer*4 + 0)*NF + f];
    float C3 = cvt[C3_OFF + (layer*4 + 0)*NF + f];
    float g0 = 1.0f + C1*n0 + C2*n0*n0 + C3*n0*n0*n0;
    float n1 = a1*a1 + a2*a2 + a3*a3;
    float D1 = cvt[C1_OFF + (layer*4 + 1)*NF + f];
    float D2 = cvt[C2_OFF + (layer*4 + 1)*NF + f];
    float D3 = cvt[C3_OFF + (layer*4 + 1)*NF + f];
    float g1 = 1.0f + D1*n1 + D2*n1*n1 + D3*n1*n1*n1;
    Ash[0][f] = a0 * g0;
    Ash[1][f] = a1 * g1;
    Ash[2][f] = a2 * g1;
    Ash[3][f] = a3 * g1;
  }
  __syncthreads();

  const float* M0 = cvt + M0_OFF + layer*NF*NF;
  const float* M1 = cvt + M1_OFF + layer*NF*NF;
  float sn = 0.f, v0 = 0.f, v1 = 0.f, v2 = 0.f;
  #pragma unroll 4
  for (int k = 0; k < NF; ++k) {
    float m0 = M0[k*NF + f];
    float m1 = M1[k*NF + f];
    sn += Ash[0][k] * m0;
    v0 += Ash[1][k] * m1;
    v1 += Ash[2][k] * m1;
    v2 += Ash[3][k] * m1;
  }
  scs[f] = sn;
  __syncthreads();

  if (!last) {
    const float* W = cvt + WN_OFF + (layer+1)*NF*NF;
    float acc = 0.f;
    #pragma unroll 8
    for (int k = 0; k < NF; ++k)
      acc += scs[k] * W[k*NF + f];
    z[bn*NF + f] = acc;
  }

  if (f < 16) {
    const float* G1 = cvt + G1_OFF + layer*NF*16;
    float acc = 0.f;
    #pragma unroll 8
    for (int k = 0; k < NF; ++k)
      acc += scs[k] * G1[k*16 + f];
    h16[f] = silu_fast(acc);
  }
  __syncthreads();
  const float* G2 = cvt + G2_OFF + layer*16*NF;
  float gate = 0.f;
  #pragma unroll
  for (int j = 0; j < 16; ++j)
    gate += h16[j] * G2[j*NF + f];
  float gv = gate * cvt[WV_OFF + layer*NF + f];

  vec[((size_t)bn*3 + 0)*NF + f] = v0;
  vec[((size_t)bn*3 + 1)*NF + f] = v1;
  vec[((size_t)bn*3 + 2)*NF + f] = v2;

  float p0 = v0*gv, p1 = v1*gv, p2 = v2*gv;
  #pragma unroll
  for (int off = 32; off > 0; off >>= 1) {
    p0 += __shfl_down(p0, off, 64);
    p1 += __shfl_down(p1, off, 64);
    p2 += __shfl_down(p2, off, 64);
  }
  int wave = f >> 6;
  if ((f & 63) == 0) { red[wave][0] = p0; red[wave][1] = p1; red[wave][2] = p2; }
  __syncthreads();
  if (f == 0) {
    float m0 = red[0][0] + red[1][0];
    float m1 = red[0][1] + red[1][1];
    float m2 = red[0][2] + red[1][2];
    float px = pos_cur[bn*3+0] + m0;
    float py = pos_cur[bn*3+1] + m1;
    float pz = pos_cur[bn*3+2] + m2;
    pos_cur[bn*3+0] = px;
    pos_cur[bn*3+1] = py;
    pos_cur[bn*3+2] = pz;
    if (last) {
      float ox = px - cvt[POS_OFF + bn*3+0];
      float oy = py - cvt[POS_OFF + bn*3+1];
      float oz = pz - cvt[POS_OFF + bn*3+2];
      if (*flag) {
        bf16* o = (bf16*)out;
        o[bn*3+0] = __float2bfloat16(ox);
        o[bn*3+1] = __float2bfloat16(oy);
        o[bn*3+2] = __float2bfloat16(oz);
      } else {
        float* o = (float*)out;
        o[bn*3+0] = ox;
        o[bn*3+1] = oy;
        o[bn*3+2] = oz;
      }
    }
  }
}

// ---------------------------------------------------------------------------
extern "C" void kernel_launch(void* const* d_in, const int* in_sizes, int n_in,
                              void* d_out, int out_size, void* d_ws, size_t ws_size,
                              hipStream_t stream)
{
  (void)in_sizes; (void)n_in; (void)out_size; (void)ws_size;
  const int* nfeat = (const int*)d_in[1];

  float* ws      = (float*)d_ws;
  int*   flag    = (int*)ws;                  // 16 floats reserved
  float* cvt     = ws + 16;                   // CVT_TOTAL floats
  float* pos_cur = cvt + CVT_TOTAL;           // 1536
  float* z       = pos_cur + NB*NN*3;         // 65536
  float* vec     = z + NB*NN*NF;              // 196608
  float* Ag      = vec + NB*NN*3*NF;          // 262144
  float* env     = Ag + NB*NN*4*NF;           // 65536

  prep_convert_kernel<<<512, 256, 0, stream>>>(
      d_in[0], nfeat, d_in[2], d_in[3], d_in[4], d_in[5], d_in[6], d_in[7],
      d_in[8], d_in[9], d_in[10], d_in[11], d_in[12], d_in[13], d_in[14],
      d_in[15], d_in[16], flag, cvt, pos_cur, z, vec, env, Ag);
  for (int i = 0; i < NL; ++i) {
    edge_kernel<<<1024, 256, 0, stream>>>(pos_cur, z, vec, env, cvt, i, Ag);
    node_kernel<<<NB*NN, NF, 0, stream>>>(Ag, cvt, i, (i == NL-1) ? 1 : 0,
                                          vec, z, pos_cur, flag, d_out);
  }
}